// Round 1
// baseline (41.595 us; speedup 1.0000x reference)
//
#include <hip/hip_runtime.h>
#include <hip/hip_bf16.h>

// Problem constants (from reference): B=32, N=2048, M=16, K=32, H=in_sizes[2]
constexpr int Bc = 32;
constexpr int Nc = 2048;
constexpr int Mc = 16;
constexpr int Kc = 32;
constexpr int ROWc = Mc + 1;       // 17 floats per dgm row
constexpr float EPSc = 1e-7f;

// ---------------------------------------------------------------------------
// Kernel 0: firstzero[b] = min n such that dgm[b,n,:] is entirely zero (else INT_MAX)
// grid = (B * 8) blocks x 256 threads; each thread owns exactly one row.
// fz array (32 ints) lives at d_ws, pre-initialized to 0x7f7f7f7f via memset.
// ---------------------------------------------------------------------------
__global__ __launch_bounds__(256) void k_firstzero(const float* __restrict__ dgm,
                                                   int* __restrict__ fz) {
    int bid   = blockIdx.x;
    int b     = bid >> 3;          // 8 slices per batch
    int slice = bid & 7;
    int n     = (slice << 8) + threadIdx.x;   // 256 rows per slice

    const float* row = dgm + ((size_t)b * Nc + n) * ROWc;
    bool nz = false;
#pragma unroll
    for (int j = 0; j < ROWc; ++j) nz = nz || (row[j] != 0.0f);

    int localmin = nz ? 0x7FFFFFFF : n;
    // wave-64 min reduce
#pragma unroll
    for (int mask = 32; mask >= 1; mask >>= 1)
        localmin = min(localmin, __shfl_xor(localmin, mask));
    if ((threadIdx.x & 63) == 0)
        atomicMin(&fz[b], localmin);
}

// ---------------------------------------------------------------------------
// Kernel 1: T[b,k,m] = sum_n v[b,k,n,m] * w[b,n]   (written into d_out)
// grid = B*K blocks x 256 threads; block (b,k) reduces over all n.
// ---------------------------------------------------------------------------
__global__ __launch_bounds__(256) void k_T(const float* __restrict__ dgm,
                                           const float* __restrict__ theta,
                                           const float* __restrict__ class_w,
                                           const int* __restrict__ fz,
                                           float* __restrict__ T,
                                           int H) {
    int bk = blockIdx.x;
    int b  = bk >> 5;              // K = 32
    int k  = bk & 31;

    // theta row (uniform per block -> scalar loads)
    float th[Mc];
#pragma unroll
    for (int m = 0; m < Mc; ++m) th[m] = theta[k * Mc + m];

    int fzb = fz[b];

    float acc[Mc];
#pragma unroll
    for (int m = 0; m < Mc; ++m) acc[m] = 0.0f;

    const float* base = dgm + (size_t)b * Nc * ROWc;

    for (int n = threadIdx.x; n < Nc; n += 256) {
        if (n >= fzb) continue;                 // valid (cumprod) == 0 from here
        const float* row = base + (size_t)n * ROWc;
        float f0 = row[0];
        int h = (int)f0;                        // trunc, matches astype(int32)
        h = max(0, min(h, H - 1));
        float wv = class_w[h];
        if (wv == 0.0f) continue;

        float z[Mc];
        float zn2 = 0.0f;
#pragma unroll
        for (int m = 0; m < Mc; ++m) {
            z[m] = row[1 + m] * th[m];
            zn2  = fmaf(z[m], z[m], zn2);
        }
        float d   = 1.0f / (1.0f + sqrtf(1.0f + zn2));
        float xn2 = zn2 * d * d;                // ||x||^2 = d^2 * ||z||^2
        float xn  = sqrtf(xn2);
        float u   = fminf(xn, 1.0f - EPSc);
        float at  = 0.5f * __logf((1.0f + u) / (1.0f - u));   // atanh(u)
        float coef = at / fmaxf(xn, EPSc) * d * wv;           // v*w = coef * z
#pragma unroll
        for (int m = 0; m < Mc; ++m) acc[m] = fmaf(coef, z[m], acc[m]);
    }

    // block reduce: wave-64 shfl, then LDS across the 4 waves
#pragma unroll
    for (int m = 0; m < Mc; ++m) {
#pragma unroll
        for (int mask = 32; mask >= 1; mask >>= 1)
            acc[m] += __shfl_xor(acc[m], mask);
    }

    __shared__ float red[4][Mc];
    int wid = threadIdx.x >> 6;
    if ((threadIdx.x & 63) == 0) {
#pragma unroll
        for (int m = 0; m < Mc; ++m) red[wid][m] = acc[m];
    }
    __syncthreads();
    if (threadIdx.x < Mc) {
        int m = threadIdx.x;
        T[(size_t)bk * Mc + m] = red[0][m] + red[1][m] + red[2][m] + red[3][m];
    }
}

// ---------------------------------------------------------------------------
// Kernel 2: S = cumsum over the flattened (B*K, M) rows of T, then
//           yd = 2*xd/(1-||xd||^2), xd = tanh(||S||)*S/max(||S||,eps).
// Single block, 1024 threads. thread = (m = tid&15, seg = tid>>4).
// Each seg owns 16 consecutive rows. In-place on d_out (each thread reads
// exactly the indices it later writes; writes happen after barriers).
// ---------------------------------------------------------------------------
__global__ __launch_bounds__(1024) void k_scan(float* __restrict__ T) {
    __shared__ float buf[2][64][Mc];

    int tid = threadIdx.x;
    int m   = tid & 15;
    int seg = tid >> 4;            // 0..63, 16 rows each -> 1024 rows

    // local inclusive prefix over the 16 rows of this segment (one column)
    float p[16];
    float run = 0.0f;
#pragma unroll
    for (int j = 0; j < 16; ++j) {
        run += T[(size_t)(seg * 16 + j) * Mc + m];
        p[j] = run;
    }

    // Hillis-Steele inclusive scan of segment totals over seg (64), per m
    buf[0][seg][m] = run;
    __syncthreads();
    int src = 0;
#pragma unroll
    for (int d = 1; d < 64; d <<= 1) {
        float v = buf[src][seg][m];
        if (seg >= d) v += buf[src][seg - d][m];
        buf[src ^ 1][seg][m] = v;
        __syncthreads();
        src ^= 1;
    }
    float off = (seg > 0) ? buf[src][seg - 1][m] : 0.0f;

#pragma unroll
    for (int j = 0; j < 16; ++j) {
        float S = off + p[j];
        // sn2 = sum over the 16 m-lanes (xor masks stay within 16-lane groups)
        float sn2 = S * S;
        sn2 += __shfl_xor(sn2, 1);
        sn2 += __shfl_xor(sn2, 2);
        sn2 += __shfl_xor(sn2, 4);
        sn2 += __shfl_xor(sn2, 8);
        float sn = sqrtf(sn2);
        float c  = tanhf(sn) / fmaxf(sn, EPSc);
        float sx2 = c * c * sn2;               // == sum(xd^2)
        float yd = 2.0f * c * S / (1.0f - sx2);
        T[(size_t)(seg * 16 + j) * Mc + m] = yd;
    }
}

// ---------------------------------------------------------------------------
extern "C" void kernel_launch(void* const* d_in, const int* in_sizes, int n_in,
                              void* d_out, int out_size, void* d_ws, size_t ws_size,
                              hipStream_t stream) {
    const float* dgm     = (const float*)d_in[0];   // (B, N, 17)
    const float* theta   = (const float*)d_in[1];   // (K, M)
    const float* class_w = (const float*)d_in[2];   // (H,)
    int H = in_sizes[2];

    int*   fz  = (int*)d_ws;          // 32 ints
    float* out = (float*)d_out;       // holds T after k_T, then yd after k_scan

    // init firstzero sentinels (0x7f7f7f7f > N); memset nodes are capturable
    hipMemsetAsync(d_ws, 0x7f, Bc * sizeof(int), stream);

    k_firstzero<<<Bc * 8, 256, 0, stream>>>(dgm, fz);
    k_T<<<Bc * Kc, 256, 0, stream>>>(dgm, theta, class_w, fz, out, H);
    k_scan<<<1, 1024, 0, stream>>>(out);
}

// Round 2
// 37.056 us; speedup vs baseline: 1.1225x; 1.1225x over previous
//
#include <hip/hip_runtime.h>
#include <hip/hip_bf16.h>

// Problem constants (from reference): B=32, N=2048, M=16, K=32, H=in_sizes[2]
constexpr int Bc = 32;
constexpr int Nc = 2048;
constexpr int Mc = 16;
constexpr int Kc = 32;
constexpr int ROWc = Mc + 1;       // 17 floats per dgm row
constexpr float EPSc = 1e-7f;

// ---------------------------------------------------------------------------
// Kernel 0 (prep): per 256-row slice, (a) transpose dgm[b, n0:n0+256, 0:17]
// into SoA dgmT[b][j][n] (coalesced writes), (b) compute the slice-local
// first-all-zero-row index into fzpart[bid] (plain store, no init needed).
// grid = B*8 = 256 blocks x 256 threads.
// ---------------------------------------------------------------------------
__global__ __launch_bounds__(256) void k_prep(const float* __restrict__ dgm,
                                              float* __restrict__ dgmT,
                                              int* __restrict__ fzpart) {
    __shared__ float lds[256 * ROWc];   // 17408 B
    __shared__ int wmin[4];

    int bid   = blockIdx.x;
    int b     = bid >> 3;
    int slice = bid & 7;
    int n0    = slice << 8;
    int tid   = threadIdx.x;

    // coalesced flat load of the 256x17 chunk
    const float* src = dgm + ((size_t)b * Nc + n0) * ROWc;
#pragma unroll
    for (int i = 0; i < ROWc; ++i)
        lds[tid + i * 256] = src[tid + i * 256];
    __syncthreads();

    // per-row nonzero check (row = tid); stride-17 LDS reads, conflict-free
    bool nz = false;
#pragma unroll
    for (int j = 0; j < ROWc; ++j) nz = nz || (lds[tid * ROWc + j] != 0.0f);
    int localmin = nz ? 0x7FFFFFFF : (n0 + tid);
#pragma unroll
    for (int mask = 32; mask >= 1; mask >>= 1)
        localmin = min(localmin, __shfl_xor(localmin, mask));
    if ((tid & 63) == 0) wmin[tid >> 6] = localmin;

    // transposed coalesced writes: dgmT[b][j][n0+tid]
#pragma unroll
    for (int j = 0; j < ROWc; ++j)
        dgmT[((size_t)b * ROWc + j) * Nc + n0 + tid] = lds[tid * ROWc + j];

    __syncthreads();
    if (tid == 0)
        fzpart[bid] = min(min(wmin[0], wmin[1]), min(wmin[2], wmin[3]));
}

// ---------------------------------------------------------------------------
// Kernel 1: T[b,k,m] = sum_n v[b,k,n,m] * w[b,n]   (written into d_out)
// grid = B*K blocks x 256 threads; block (b,k) reduces over all n.
// Reads SoA dgmT -> all loads coalesced.
// ---------------------------------------------------------------------------
__global__ __launch_bounds__(256) void k_T(const float* __restrict__ dgmT,
                                           const float* __restrict__ theta,
                                           const float* __restrict__ class_w,
                                           const int* __restrict__ fzpart,
                                           float* __restrict__ T,
                                           int H) {
    int bk = blockIdx.x;
    int b  = bk >> 5;              // K = 32
    int k  = bk & 31;

    // theta row (uniform per block -> scalar loads)
    float th[Mc];
#pragma unroll
    for (int m = 0; m < Mc; ++m) th[m] = theta[k * Mc + m];

    int fzb = 0x7FFFFFFF;
#pragma unroll
    for (int i = 0; i < 8; ++i) fzb = min(fzb, fzpart[b * 8 + i]);

    float acc[Mc];
#pragma unroll
    for (int m = 0; m < Mc; ++m) acc[m] = 0.0f;

    const float* base = dgmT + (size_t)b * ROWc * Nc;   // [j][n]

    for (int c = 0; c < Nc; c += 256) {
        int n = c + threadIdx.x;
        if (n >= fzb) continue;                 // valid (cumprod) == 0 from here
        float f0 = base[n];                     // j = 0 (hom)
        int h = (int)f0;                        // trunc, matches astype(int32)
        h = max(0, min(h, H - 1));
        float wv = class_w[h];
        if (wv == 0.0f) continue;

        float z[Mc];
        float zn2 = 0.0f;
#pragma unroll
        for (int m = 0; m < Mc; ++m) {
            z[m] = base[(size_t)(1 + m) * Nc + n] * th[m];
            zn2  = fmaf(z[m], z[m], zn2);
        }
        float d   = 1.0f / (1.0f + sqrtf(1.0f + zn2));
        float xn2 = zn2 * d * d;                // ||x||^2 = d^2 * ||z||^2
        float xn  = sqrtf(xn2);
        float u   = fminf(xn, 1.0f - EPSc);
        float at  = 0.5f * __logf((1.0f + u) / (1.0f - u));   // atanh(u)
        float coef = at / fmaxf(xn, EPSc) * d * wv;           // v*w = coef * z
#pragma unroll
        for (int m = 0; m < Mc; ++m) acc[m] = fmaf(coef, z[m], acc[m]);
    }

    // block reduce: wave-64 shfl, then LDS across the 4 waves
#pragma unroll
    for (int m = 0; m < Mc; ++m) {
#pragma unroll
        for (int mask = 32; mask >= 1; mask >>= 1)
            acc[m] += __shfl_xor(acc[m], mask);
    }

    __shared__ float red[4][Mc];
    int wid = threadIdx.x >> 6;
    if ((threadIdx.x & 63) == 0) {
#pragma unroll
        for (int m = 0; m < Mc; ++m) red[wid][m] = acc[m];
    }
    __syncthreads();
    if (threadIdx.x < Mc) {
        int m = threadIdx.x;
        T[(size_t)bk * Mc + m] = red[0][m] + red[1][m] + red[2][m] + red[3][m];
    }
}

// ---------------------------------------------------------------------------
// Kernel 2: S = cumsum over the flattened (B*K, M) rows of T, then
//           yd = 2*xd/(1-||xd||^2), xd = tanh(||S||)*S/max(||S||,eps).
// Single block, 1024 threads. thread = (m = tid&15, seg = tid>>4).
// ---------------------------------------------------------------------------
__global__ __launch_bounds__(1024) void k_scan(float* __restrict__ T) {
    __shared__ float buf[2][64][Mc];

    int tid = threadIdx.x;
    int m   = tid & 15;
    int seg = tid >> 4;            // 0..63, 16 rows each -> 1024 rows

    // local inclusive prefix over the 16 rows of this segment (one column)
    float p[16];
    float run = 0.0f;
#pragma unroll
    for (int j = 0; j < 16; ++j) {
        run += T[(size_t)(seg * 16 + j) * Mc + m];
        p[j] = run;
    }

    // Hillis-Steele inclusive scan of segment totals over seg (64), per m
    buf[0][seg][m] = run;
    __syncthreads();
    int src = 0;
#pragma unroll
    for (int d = 1; d < 64; d <<= 1) {
        float v = buf[src][seg][m];
        if (seg >= d) v += buf[src][seg - d][m];
        buf[src ^ 1][seg][m] = v;
        __syncthreads();
        src ^= 1;
    }
    float off = (seg > 0) ? buf[src][seg - 1][m] : 0.0f;

#pragma unroll
    for (int j = 0; j < 16; ++j) {
        float S = off + p[j];
        float sn2 = S * S;
        sn2 += __shfl_xor(sn2, 1);
        sn2 += __shfl_xor(sn2, 2);
        sn2 += __shfl_xor(sn2, 4);
        sn2 += __shfl_xor(sn2, 8);
        float sn = sqrtf(sn2);
        float c  = tanhf(sn) / fmaxf(sn, EPSc);
        float sx2 = c * c * sn2;               // == sum(xd^2)
        float yd = 2.0f * c * S / (1.0f - sx2);
        T[(size_t)(seg * 16 + j) * Mc + m] = yd;
    }
}

// ---------------------------------------------------------------------------
extern "C" void kernel_launch(void* const* d_in, const int* in_sizes, int n_in,
                              void* d_out, int out_size, void* d_ws, size_t ws_size,
                              hipStream_t stream) {
    const float* dgm     = (const float*)d_in[0];   // (B, N, 17)
    const float* theta   = (const float*)d_in[1];   // (K, M)
    const float* class_w = (const float*)d_in[2];   // (H,)
    int H = in_sizes[2];

    int*   fzpart = (int*)d_ws;                     // 256 ints
    float* dgmT   = (float*)d_ws + 256;             // 32*17*2048 floats = 4.46 MB
    float* out    = (float*)d_out;                  // T, then yd in place

    k_prep<<<Bc * 8, 256, 0, stream>>>(dgm, dgmT, fzpart);
    k_T<<<Bc * Kc, 256, 0, stream>>>(dgmT, theta, class_w, fzpart, out, H);
    k_scan<<<1, 1024, 0, stream>>>(out);
}

// Round 3
// 33.565 us; speedup vs baseline: 1.2392x; 1.1040x over previous
//
#include <hip/hip_runtime.h>
#include <hip/hip_bf16.h>

// Problem constants (from reference): B=32, N=2048, M=16, K=32, H=in_sizes[2]
constexpr int Bc = 32;
constexpr int Nc = 2048;
constexpr int Mc = 16;
constexpr int Kc = 32;
constexpr int ROWc = Mc + 1;       // 17 floats per dgm row
constexpr float EPSc = 1e-7f;

// ---------------------------------------------------------------------------
// Kernel A (fused validity + T): one block per (b,k), 256 threads.
// Per 256-row chunk:
//   1. stage dgm[b, c0:c0+256, :] into LDS (coalesced dword loads)
//   2. each thread reads its own row (stride-17 LDS = 2-way conflict, free)
//   3. block-min of first all-zero row index -> running fzb
//   4. threads with n < fzb accumulate their row's contribution (regs only)
//   5. once c0+256 >= fzb, remaining chunks are all invalid -> break
// T[b,k,m] written to d_out.
// ---------------------------------------------------------------------------
__global__ __launch_bounds__(256, 4) void k_fused(const float* __restrict__ dgm,
                                                  const float* __restrict__ theta,
                                                  const float* __restrict__ class_w,
                                                  float* __restrict__ T,
                                                  int H) {
    __shared__ float lds[256 * ROWc];   // 17408 B
    __shared__ int   wmin[4];
    __shared__ float red[4][Mc];

    int bk  = blockIdx.x;
    int b   = bk >> 5;                  // K = 32
    int k   = bk & 31;
    int tid = threadIdx.x;
    int wid = tid >> 6;

    float th[Mc];
#pragma unroll
    for (int m = 0; m < Mc; ++m) th[m] = theta[k * Mc + m];

    float acc[Mc];
#pragma unroll
    for (int m = 0; m < Mc; ++m) acc[m] = 0.0f;

    const float* base = dgm + (size_t)b * Nc * ROWc;
    int fzb = 0x7FFFFFFF;

    for (int c0 = 0; c0 < Nc; c0 += 256) {
        // 1. stage chunk (256 rows x 17 floats), fully coalesced
        const float* src = base + (size_t)c0 * ROWc;
#pragma unroll
        for (int i = 0; i < ROWc; ++i)
            lds[tid + i * 256] = src[tid + i * 256];
        __syncthreads();

        // 2. own row into registers
        float r[ROWc];
#pragma unroll
        for (int j = 0; j < ROWc; ++j) r[j] = lds[tid * ROWc + j];

        // 3. chunk-local first-zero-row reduce
        bool nz = false;
#pragma unroll
        for (int j = 0; j < ROWc; ++j) nz = nz || (r[j] != 0.0f);
        int lm = nz ? 0x7FFFFFFF : (c0 + tid);
#pragma unroll
        for (int mask = 32; mask >= 1; mask >>= 1)
            lm = min(lm, __shfl_xor(lm, mask));
        if ((tid & 63) == 0) wmin[wid] = lm;
        __syncthreads();
        fzb = min(fzb, min(min(wmin[0], wmin[1]), min(wmin[2], wmin[3])));

        // 4. accumulate valid rows (data already in registers)
        int n = c0 + tid;
        if (n < fzb) {
            int h = (int)r[0];                  // trunc == astype(int32)
            h = max(0, min(h, H - 1));
            float wv = class_w[h];

            float z[Mc];
            float zn2 = 0.0f;
#pragma unroll
            for (int m = 0; m < Mc; ++m) {
                z[m] = r[1 + m] * th[m];
                zn2  = fmaf(z[m], z[m], zn2);
            }
            float d   = 1.0f / (1.0f + sqrtf(1.0f + zn2));
            float xn2 = zn2 * d * d;            // ||x||^2 = d^2 ||z||^2
            float xn  = sqrtf(xn2);
            float u   = fminf(xn, 1.0f - EPSc);
            float at  = 0.5f * __logf((1.0f + u) / (1.0f - u));  // atanh
            float coef = at / fmaxf(xn, EPSc) * d * wv;          // v*w = coef*z
#pragma unroll
            for (int m = 0; m < Mc; ++m) acc[m] = fmaf(coef, z[m], acc[m]);
        }

        // 5. everything past fzb is invalid
        if (c0 + 256 >= fzb) break;
        __syncthreads();   // protect lds/wmin before next chunk overwrites
    }

    // block reduce: wave-64 shfl, then LDS across the 4 waves
#pragma unroll
    for (int m = 0; m < Mc; ++m) {
#pragma unroll
        for (int mask = 32; mask >= 1; mask >>= 1)
            acc[m] += __shfl_xor(acc[m], mask);
    }
    __syncthreads();       // wmin/lds done; reuse barrier before red writes
    if ((tid & 63) == 0) {
#pragma unroll
        for (int m = 0; m < Mc; ++m) red[wid][m] = acc[m];
    }
    __syncthreads();
    if (tid < Mc) {
        int m = tid;
        T[(size_t)bk * Mc + m] = red[0][m] + red[1][m] + red[2][m] + red[3][m];
    }
}

// ---------------------------------------------------------------------------
// Kernel B: S = cumsum over flattened (B*K, M) rows of T, then
//           yd = 2*xd/(1-||xd||^2), xd = tanh(||S||)*S/max(||S||,eps).
// Single block, 1024 threads. thread = (m = tid&15, seg = tid>>4).
// ---------------------------------------------------------------------------
__global__ __launch_bounds__(1024) void k_scan(float* __restrict__ T) {
    __shared__ float buf[2][64][Mc];

    int tid = threadIdx.x;
    int m   = tid & 15;
    int seg = tid >> 4;            // 0..63, 16 rows each -> 1024 rows

    float p[16];
    float run = 0.0f;
#pragma unroll
    for (int j = 0; j < 16; ++j) {
        run += T[(size_t)(seg * 16 + j) * Mc + m];
        p[j] = run;
    }

    buf[0][seg][m] = run;
    __syncthreads();
    int src = 0;
#pragma unroll
    for (int d = 1; d < 64; d <<= 1) {
        float v = buf[src][seg][m];
        if (seg >= d) v += buf[src][seg - d][m];
        buf[src ^ 1][seg][m] = v;
        __syncthreads();
        src ^= 1;
    }
    float off = (seg > 0) ? buf[src][seg - 1][m] : 0.0f;

#pragma unroll
    for (int j = 0; j < 16; ++j) {
        float S = off + p[j];
        float sn2 = S * S;
        sn2 += __shfl_xor(sn2, 1);
        sn2 += __shfl_xor(sn2, 2);
        sn2 += __shfl_xor(sn2, 4);
        sn2 += __shfl_xor(sn2, 8);
        float sn = sqrtf(sn2);
        float c  = tanhf(sn) / fmaxf(sn, EPSc);
        float sx2 = c * c * sn2;               // == sum(xd^2)
        float yd = 2.0f * c * S / (1.0f - sx2);
        T[(size_t)(seg * 16 + j) * Mc + m] = yd;
    }
}

// ---------------------------------------------------------------------------
extern "C" void kernel_launch(void* const* d_in, const int* in_sizes, int n_in,
                              void* d_out, int out_size, void* d_ws, size_t ws_size,
                              hipStream_t stream) {
    const float* dgm     = (const float*)d_in[0];   // (B, N, 17)
    const float* theta   = (const float*)d_in[1];   // (K, M)
    const float* class_w = (const float*)d_in[2];   // (H,)
    int H = in_sizes[2];

    float* out = (float*)d_out;                     // T, then yd in place

    k_fused<<<Bc * Kc, 256, 0, stream>>>(dgm, theta, class_w, out, H);
    k_scan<<<1, 1024, 0, stream>>>(out);
}